// Round 7
// baseline (142.296 us; speedup 1.0000x reference)
//
#include <hip/hip_runtime.h>

#define N_NODES 100000
#define N_EDGES 1600000
#define D_FEAT 32

#define BSH 7                 // bucket = dst >> 7  (128 nodes per bucket)
#define BMASK 127
#define NB 782                // ceil(100000/128)
#define CAPB 2432             // per-bucket capacity (mean 2048, ~8.5 sigma pad)

#define P1_BS 512
#define P1_TILE 4096          // 8 edges/thread
#define P1_CAP 16             // staging per bucket per block (mean ~5.2)

// ws layout (4-byte words):
//   cursorA [1024]        int    per-bucket fill cursors (init to b*CAPB)
//   srange  [2*N_NODES]   int2   (start,end) absolute indices into ssrc
//   dinv    [N_NODES]     float
//   ssrc    [NB*CAPB]     int    srcs, dst-sorted within padded bucket regions
//   pairs   [NB*CAPB]     int    packed (src<<7)|(dst&127), bucket-grouped
//   sfeat   [N_NODES*32]  float  feat*dinv (written by sort_kernel)

__global__ void init_kernel(int* __restrict__ cursorA) {
    int b = blockIdx.x * blockDim.x + threadIdx.x;
    if (b < NB) cursorA[b] = b * CAPB;
}

// Pass 1: bucket edges by dst>>7 with LDS staging -> coalesced runs into
// fixed per-bucket regions.
__global__ void __launch_bounds__(P1_BS)
bucket_kernel(const int* __restrict__ edge_src,
              const int* __restrict__ edge_dst,
              int* __restrict__ cursorA,
              int* __restrict__ pairs, int n_edges) {
    __shared__ int s_cnt[NB];
    __shared__ int s_base[NB];
    __shared__ int s_off[NB + 1];
    __shared__ int s_buf[NB * P1_CAP];   // 782*16*4 = 50 KB

    int tile = blockIdx.x * P1_TILE;
    if (tile >= n_edges) return;

    for (int b = threadIdx.x; b < NB; b += P1_BS) s_cnt[b] = 0;
    __syncthreads();

    const int4* src4 = reinterpret_cast<const int4*>(edge_src);
    const int4* dst4 = reinterpret_cast<const int4*>(edge_dst);
    int tileq = blockIdx.x * (P1_TILE / 4);
    #pragma unroll
    for (int j = 0; j < P1_TILE / 4 / P1_BS; ++j) {
        int iq = tileq + j * P1_BS + threadIdx.x;
        if (iq * 4 < n_edges) {
            int4 sv = src4[iq];
            int4 dv = dst4[iq];
            int ss[4] = {sv.x, sv.y, sv.z, sv.w};
            int dd[4] = {dv.x, dv.y, dv.z, dv.w};
            #pragma unroll
            for (int u = 0; u < 4; ++u) {
                int b = dd[u] >> BSH;
                int packed = (ss[u] << BSH) | (dd[u] & BMASK);
                int p = atomicAdd(&s_cnt[b], 1);
                if (p < P1_CAP) {
                    s_buf[b * P1_CAP + p] = packed;
                } else {
                    int gp = atomicAdd(&cursorA[b], 1);   // rare overflow
                    pairs[gp] = packed;
                }
            }
        }
    }
    __syncthreads();

    for (int b = threadIdx.x; b < NB; b += P1_BS) {
        int c = min(s_cnt[b], P1_CAP);
        s_base[b] = atomicAdd(&cursorA[b], c);
        s_cnt[b] = c;
    }
    __syncthreads();
    if (threadIdx.x == 0) {
        int acc = 0;
        for (int b = 0; b < NB; ++b) { s_off[b] = acc; acc += s_cnt[b]; }
        s_off[NB] = acc;
    }
    __syncthreads();

    int total = s_off[NB];
    for (int t = threadIdx.x; t < total; t += P1_BS) {
        int lo = 0, hi = NB;
        while (hi - lo > 1) {
            int mid = (lo + hi) >> 1;
            if (t >= s_off[mid]) lo = mid; else hi = mid;
        }
        int idx = t - s_off[lo];
        pairs[s_base[lo] + idx] = s_buf[lo * P1_CAP + idx];
    }
}

// Pass 2: one WG per bucket — LDS counting sort by dst (128 bins).
// Produces dst-sorted ssrc, (start,end) ranges, dinv, and sfeat rows.
__global__ void __launch_bounds__(256)
sort_kernel(const int* __restrict__ pairs,
            const int* __restrict__ cursorA,
            const float* __restrict__ feat,
            int* __restrict__ ssrc,
            int2* __restrict__ srange,
            float* __restrict__ dinv,
            float* __restrict__ sfeat) {
    __shared__ int buf[CAPB];     // 9.5 KB
    __shared__ int outb[CAPB];    // 9.5 KB
    __shared__ int h[128];
    __shared__ int sc[128];
    __shared__ int cur[128];
    __shared__ float dv_s[128];

    int b = blockIdx.x;
    int t = threadIdx.x;
    int base = b * CAPB;
    int cnt = min(cursorA[b] - base, CAPB);

    if (t < 128) h[t] = 0;
    __syncthreads();
    for (int i = t; i < cnt; i += 256) {
        int p = pairs[base + i];
        buf[i] = p;
        atomicAdd(&h[p & BMASK], 1);
    }
    __syncthreads();

    // exclusive scan of h (128 bins)
    int v = 0;
    if (t < 128) { v = h[t]; sc[t] = v; }
    __syncthreads();
    for (int off = 1; off < 128; off <<= 1) {
        int x = 0;
        if (t < 128 && t >= off) x = sc[t - off];
        __syncthreads();
        if (t < 128) sc[t] += x;
        __syncthreads();
    }
    if (t < 128) {
        int ex = sc[t] - v;
        cur[t] = ex;
        int node = (b << BSH) + t;
        if (node < N_NODES) {
            srange[node] = make_int2(base + ex, base + ex + v);
            float dvv = rsqrtf(fmaxf((float)v, 1.0f));
            dinv[node] = dvv;
            dv_s[t] = dvv;
        }
    }
    __syncthreads();

    for (int i = t; i < cnt; i += 256) {
        int p = buf[i];
        int pos = atomicAdd(&cur[p & BMASK], 1);
        outb[pos] = p >> BSH;
    }
    __syncthreads();
    for (int i = t; i < cnt; i += 256)
        ssrc[base + i] = outb[i];

    // sfeat rows for this bucket's nodes: sfeat[n] = feat[n] * dinv[n]
    const float4* feat4 = reinterpret_cast<const float4*>(feat);
    float4* sf4 = reinterpret_cast<float4*>(sfeat);
    for (int idx = t; idx < 128 * 8; idx += 256) {
        int nl = idx >> 3;
        int node = (b << BSH) + nl;
        if (node >= N_NODES) continue;
        float dvv = dv_s[nl];
        float4 fv = feat4[node * 8 + (idx & 7)];
        fv.x *= dvv; fv.y *= dvv; fv.z *= dvv; fv.w *= dvv;
        sf4[node * 8 + (idx & 7)] = fv;
    }
}

// Gather over pre-scaled features; fused Bernstein epilogue.
__global__ void gather_sf_kernel(const float* __restrict__ feat,
                                 const float* __restrict__ sfeat,
                                 const int2* __restrict__ srange,
                                 const int* __restrict__ ssrc,
                                 const float* __restrict__ dinv,
                                 float* __restrict__ out) {
    int gid = blockIdx.x * blockDim.x + threadIdx.x;
    int node = gid >> 3;
    int fq = gid & 7;
    if (node >= N_NODES) return;
    int2 se = srange[node];
    int k = se.x, en = se.y;
    const float4* sf4 = reinterpret_cast<const float4*>(sfeat);
    float4 acc = make_float4(0.f, 0.f, 0.f, 0.f);
    for (; k + 3 < en; k += 4) {
        int s0 = ssrc[k],     s1 = ssrc[k + 1];
        int s2 = ssrc[k + 2], s3 = ssrc[k + 3];
        float4 f0 = sf4[s0 * 8 + fq];
        float4 f1 = sf4[s1 * 8 + fq];
        float4 f2 = sf4[s2 * 8 + fq];
        float4 f3 = sf4[s3 * 8 + fq];
        acc.x += f0.x + f1.x + f2.x + f3.x;
        acc.y += f0.y + f1.y + f2.y + f3.y;
        acc.z += f0.z + f1.z + f2.z + f3.z;
        acc.w += f0.w + f1.w + f2.w + f3.w;
    }
    for (; k < en; ++k) {
        int s = ssrc[k];
        float4 fv = sf4[s * 8 + fq];
        acc.x += fv.x; acc.y += fv.y; acc.z += fv.z; acc.w += fv.w;
    }
    float dvn = dinv[node];
    float4 fv = reinterpret_cast<const float4*>(feat)[node * 8 + fq];
    float4 o;
    float yx = 0.5f * (fv.x - acc.x * dvn);
    float yy = 0.5f * (fv.y - acc.y * dvn);
    float yz = 0.5f * (fv.z - acc.z * dvn);
    float yw = 0.5f * (fv.w - acc.w * dvn);
    o.x = 2.0f * yx * (fv.x - yx);
    o.y = 2.0f * yy * (fv.y - yy);
    o.z = 2.0f * yz * (fv.z - yz);
    o.w = 2.0f * yw * (fv.w - yw);
    reinterpret_cast<float4*>(out)[gid] = o;
}

extern "C" void kernel_launch(void* const* d_in, const int* in_sizes, int n_in,
                              void* d_out, int out_size, void* d_ws, size_t ws_size,
                              hipStream_t stream) {
    const float* feat = (const float*)d_in[0];
    const int* edge_src = (const int*)d_in[1];
    const int* edge_dst = (const int*)d_in[2];
    float* out = (float*)d_out;

    int* ws = (int*)d_ws;
    int* cursorA  = ws;                           // 1024
    int2* srange  = (int2*)(cursorA + 1024);      // N_NODES int2
    float* dinv   = (float*)(srange + N_NODES);   // N_NODES
    int* ssrc     = (int*)(dinv + N_NODES);       // NB*CAPB
    int* pairs    = ssrc + NB * CAPB;             // NB*CAPB
    float* sfeat  = (float*)(pairs + NB * CAPB);  // N_NODES*32

    init_kernel<<<1, 1024, 0, stream>>>(cursorA);
    {
        int blocks = (N_EDGES + P1_TILE - 1) / P1_TILE;   // 391
        bucket_kernel<<<blocks, P1_BS, 0, stream>>>(edge_src, edge_dst,
                                                    cursorA, pairs, N_EDGES);
    }
    sort_kernel<<<NB, 256, 0, stream>>>(pairs, cursorA, feat, ssrc, srange,
                                        dinv, sfeat);
    {
        int total = N_NODES * 8;
        int blocks = (total + 255) / 256;
        gather_sf_kernel<<<blocks, 256, 0, stream>>>(feat, sfeat, srange,
                                                     ssrc, dinv, out);
    }
}

// Round 8
// 131.932 us; speedup vs baseline: 1.0786x; 1.0786x over previous
//
#include <hip/hip_runtime.h>

#define N_NODES 100000
#define N_EDGES 1600000
#define D_FEAT 32

#define BSH 7                 // bucket = dst >> 7  (128 nodes per bucket)
#define BMASK 127
#define NB 782                // ceil(100000/128)
#define CAPB 2432             // per-bucket capacity (mean 2048, ~8.5 sigma pad)

#define P1_BS 512
#define P1_TILE 4096          // 8 edges/thread
#define P1_CAP 16             // staging per bucket per block (mean ~5.2)

// ws layout (4-byte words):
//   cursorA [1024]        int    per-bucket fill cursors (init to b*CAPB)
//   srange  [2*N_NODES]   int2   (start,end) absolute indices into ssrc
//   dinv    [N_NODES]     float
//   ssrc    [NB*CAPB]     int    srcs, dst-sorted within padded bucket regions
//   pairs   [NB*CAPB]     int    packed (src<<7)|(dst&127), bucket-grouped
//   sfeat   [N_NODES*16]  uint   bf16-packed feat*dinv (2 feats per uint)

static __device__ __forceinline__ unsigned pack_bf16(float a, float b) {
    unsigned ua = __float_as_uint(a);
    unsigned ub = __float_as_uint(b);
    ua = (ua + 0x7FFFu + ((ua >> 16) & 1u)) >> 16;   // RNE
    ub = (ub + 0x7FFFu + ((ub >> 16) & 1u)) >> 16;
    return (ua & 0xFFFFu) | (ub << 16);
}

__global__ void init_kernel(int* __restrict__ cursorA) {
    int b = blockIdx.x * blockDim.x + threadIdx.x;
    if (b < NB) cursorA[b] = b * CAPB;
}

// Pass 1: bucket edges by dst>>7 with LDS staging -> coalesced runs into
// fixed per-bucket regions.
__global__ void __launch_bounds__(P1_BS)
bucket_kernel(const int* __restrict__ edge_src,
              const int* __restrict__ edge_dst,
              int* __restrict__ cursorA,
              int* __restrict__ pairs, int n_edges) {
    __shared__ int s_cnt[NB];
    __shared__ int s_base[NB];
    __shared__ int s_off[NB + 1];
    __shared__ int s_buf[NB * P1_CAP];   // 782*16*4 = 50 KB

    int tile = blockIdx.x * P1_TILE;
    if (tile >= n_edges) return;

    for (int b = threadIdx.x; b < NB; b += P1_BS) s_cnt[b] = 0;
    __syncthreads();

    const int4* src4 = reinterpret_cast<const int4*>(edge_src);
    const int4* dst4 = reinterpret_cast<const int4*>(edge_dst);
    int tileq = blockIdx.x * (P1_TILE / 4);
    #pragma unroll
    for (int j = 0; j < P1_TILE / 4 / P1_BS; ++j) {
        int iq = tileq + j * P1_BS + threadIdx.x;
        if (iq * 4 < n_edges) {
            int4 sv = src4[iq];
            int4 dv = dst4[iq];
            int ss[4] = {sv.x, sv.y, sv.z, sv.w};
            int dd[4] = {dv.x, dv.y, dv.z, dv.w};
            #pragma unroll
            for (int u = 0; u < 4; ++u) {
                int b = dd[u] >> BSH;
                int packed = (ss[u] << BSH) | (dd[u] & BMASK);
                int p = atomicAdd(&s_cnt[b], 1);
                if (p < P1_CAP) {
                    s_buf[b * P1_CAP + p] = packed;
                } else {
                    int gp = atomicAdd(&cursorA[b], 1);   // rare overflow
                    pairs[gp] = packed;
                }
            }
        }
    }
    __syncthreads();

    for (int b = threadIdx.x; b < NB; b += P1_BS) {
        int c = min(s_cnt[b], P1_CAP);
        s_base[b] = atomicAdd(&cursorA[b], c);
        s_cnt[b] = c;
    }
    __syncthreads();
    if (threadIdx.x == 0) {
        int acc = 0;
        for (int b = 0; b < NB; ++b) { s_off[b] = acc; acc += s_cnt[b]; }
        s_off[NB] = acc;
    }
    __syncthreads();

    int total = s_off[NB];
    for (int t = threadIdx.x; t < total; t += P1_BS) {
        int lo = 0, hi = NB;
        while (hi - lo > 1) {
            int mid = (lo + hi) >> 1;
            if (t >= s_off[mid]) lo = mid; else hi = mid;
        }
        int idx = t - s_off[lo];
        pairs[s_base[lo] + idx] = s_buf[lo * P1_CAP + idx];
    }
}

// Pass 2: one WG per bucket — LDS counting sort by dst (128 bins).
// Produces dst-sorted ssrc, (start,end) ranges, dinv, and bf16 sfeat rows.
__global__ void __launch_bounds__(256)
sort_kernel(const int* __restrict__ pairs,
            const int* __restrict__ cursorA,
            const float* __restrict__ feat,
            int* __restrict__ ssrc,
            int2* __restrict__ srange,
            float* __restrict__ dinv,
            unsigned* __restrict__ sfeat) {
    __shared__ int buf[CAPB];     // 9.5 KB
    __shared__ int outb[CAPB];    // 9.5 KB
    __shared__ int h[128];
    __shared__ int sc[128];
    __shared__ int cur[128];
    __shared__ float dv_s[128];

    int b = blockIdx.x;
    int t = threadIdx.x;
    int base = b * CAPB;
    int cnt = min(cursorA[b] - base, CAPB);

    if (t < 128) h[t] = 0;
    __syncthreads();
    for (int i = t; i < cnt; i += 256) {
        int p = pairs[base + i];
        buf[i] = p;
        atomicAdd(&h[p & BMASK], 1);
    }
    __syncthreads();

    // exclusive scan of h (128 bins)
    int v = 0;
    if (t < 128) { v = h[t]; sc[t] = v; }
    __syncthreads();
    for (int off = 1; off < 128; off <<= 1) {
        int x = 0;
        if (t < 128 && t >= off) x = sc[t - off];
        __syncthreads();
        if (t < 128) sc[t] += x;
        __syncthreads();
    }
    if (t < 128) {
        int ex = sc[t] - v;
        cur[t] = ex;
        int node = (b << BSH) + t;
        if (node < N_NODES) {
            srange[node] = make_int2(base + ex, base + ex + v);
            float dvv = rsqrtf(fmaxf((float)v, 1.0f));
            dinv[node] = dvv;
            dv_s[t] = dvv;
        }
    }
    __syncthreads();

    for (int i = t; i < cnt; i += 256) {
        int p = buf[i];
        int pos = atomicAdd(&cur[p & BMASK], 1);
        outb[pos] = p >> BSH;
    }
    __syncthreads();
    for (int i = t; i < cnt; i += 256)
        ssrc[base + i] = outb[i];

    // bf16 sfeat rows: sfeat[n] = bf16(feat[n] * dinv[n]), uint4 per 8 feats
    const float4* feat4 = reinterpret_cast<const float4*>(feat);
    uint4* sf4 = reinterpret_cast<uint4*>(sfeat);
    for (int idx = t; idx < 128 * 4; idx += 256) {
        int nl = idx >> 2;
        int q = idx & 3;
        int node = (b << BSH) + nl;
        if (node >= N_NODES) continue;
        float dvv = dv_s[nl];
        float4 fa = feat4[node * 8 + 2 * q];
        float4 fb = feat4[node * 8 + 2 * q + 1];
        uint4 pk;
        pk.x = pack_bf16(fa.x * dvv, fa.y * dvv);
        pk.y = pack_bf16(fa.z * dvv, fa.w * dvv);
        pk.z = pack_bf16(fb.x * dvv, fb.y * dvv);
        pk.w = pack_bf16(fb.z * dvv, fb.w * dvv);
        sf4[node * 4 + q] = pk;
    }
}

// Gather over bf16 pre-scaled features; fused Bernstein epilogue.
// 4 threads per node, each handles 8 features (one uint4 = 16 B per edge).
__global__ void gather_bf_kernel(const float* __restrict__ feat,
                                 const unsigned* __restrict__ sfeat,
                                 const int2* __restrict__ srange,
                                 const int* __restrict__ ssrc,
                                 const float* __restrict__ dinv,
                                 float* __restrict__ out) {
    int gid = blockIdx.x * blockDim.x + threadIdx.x;
    int node = gid >> 2;
    int q = gid & 3;
    if (node >= N_NODES) return;
    int2 se = srange[node];
    int k = se.x, en = se.y;
    const uint4* sf4 = reinterpret_cast<const uint4*>(sfeat);
    float a0 = 0.f, a1 = 0.f, a2 = 0.f, a3 = 0.f;
    float a4 = 0.f, a5 = 0.f, a6 = 0.f, a7 = 0.f;

    #define ACC(r)                                                 \
        a0 += __uint_as_float((r).x << 16);                        \
        a1 += __uint_as_float((r).x & 0xFFFF0000u);                \
        a2 += __uint_as_float((r).y << 16);                        \
        a3 += __uint_as_float((r).y & 0xFFFF0000u);                \
        a4 += __uint_as_float((r).z << 16);                        \
        a5 += __uint_as_float((r).z & 0xFFFF0000u);                \
        a6 += __uint_as_float((r).w << 16);                        \
        a7 += __uint_as_float((r).w & 0xFFFF0000u);

    for (; k + 3 < en; k += 4) {
        int s0 = ssrc[k],     s1 = ssrc[k + 1];
        int s2 = ssrc[k + 2], s3 = ssrc[k + 3];
        uint4 r0 = sf4[s0 * 4 + q];
        uint4 r1 = sf4[s1 * 4 + q];
        uint4 r2 = sf4[s2 * 4 + q];
        uint4 r3 = sf4[s3 * 4 + q];
        ACC(r0) ACC(r1) ACC(r2) ACC(r3)
    }
    for (; k < en; ++k) {
        uint4 r = sf4[ssrc[k] * 4 + q];
        ACC(r)
    }
    #undef ACC

    float dvn = dinv[node];
    const float4* feat4 = reinterpret_cast<const float4*>(feat);
    float4 fa = feat4[node * 8 + 2 * q];
    float4 fb = feat4[node * 8 + 2 * q + 1];
    float4 oa, ob;
    float y;
    y = 0.5f * (fa.x - a0 * dvn); oa.x = 2.0f * y * (fa.x - y);
    y = 0.5f * (fa.y - a1 * dvn); oa.y = 2.0f * y * (fa.y - y);
    y = 0.5f * (fa.z - a2 * dvn); oa.z = 2.0f * y * (fa.z - y);
    y = 0.5f * (fa.w - a3 * dvn); oa.w = 2.0f * y * (fa.w - y);
    y = 0.5f * (fb.x - a4 * dvn); ob.x = 2.0f * y * (fb.x - y);
    y = 0.5f * (fb.y - a5 * dvn); ob.y = 2.0f * y * (fb.y - y);
    y = 0.5f * (fb.z - a6 * dvn); ob.z = 2.0f * y * (fb.z - y);
    y = 0.5f * (fb.w - a7 * dvn); ob.w = 2.0f * y * (fb.w - y);
    float4* out4 = reinterpret_cast<float4*>(out);
    out4[node * 8 + 2 * q] = oa;
    out4[node * 8 + 2 * q + 1] = ob;
}

extern "C" void kernel_launch(void* const* d_in, const int* in_sizes, int n_in,
                              void* d_out, int out_size, void* d_ws, size_t ws_size,
                              hipStream_t stream) {
    const float* feat = (const float*)d_in[0];
    const int* edge_src = (const int*)d_in[1];
    const int* edge_dst = (const int*)d_in[2];
    float* out = (float*)d_out;

    int* ws = (int*)d_ws;
    int* cursorA   = ws;                           // 1024
    int2* srange   = (int2*)(cursorA + 1024);      // N_NODES int2
    float* dinv    = (float*)(srange + N_NODES);   // N_NODES
    int* ssrc      = (int*)(dinv + N_NODES);       // NB*CAPB
    int* pairs     = ssrc + NB * CAPB;             // NB*CAPB
    unsigned* sfeat = (unsigned*)(pairs + NB * CAPB);  // N_NODES*16

    init_kernel<<<1, 1024, 0, stream>>>(cursorA);
    {
        int blocks = (N_EDGES + P1_TILE - 1) / P1_TILE;   // 391
        bucket_kernel<<<blocks, P1_BS, 0, stream>>>(edge_src, edge_dst,
                                                    cursorA, pairs, N_EDGES);
    }
    sort_kernel<<<NB, 256, 0, stream>>>(pairs, cursorA, feat, ssrc, srange,
                                        dinv, sfeat);
    {
        int total = N_NODES * 4;
        int blocks = (total + 255) / 256;
        gather_bf_kernel<<<blocks, 256, 0, stream>>>(feat, sfeat, srange,
                                                     ssrc, dinv, out);
    }
}